// Round 4
// baseline (295.621 us; speedup 1.0000x reference)
//
#include <hip/hip_runtime.h>

// Problem constants (match reference)
#define BATCH 32
#define T_IN 1024
#define TP 1025      // T+1 (phoneme + silence token)
#define EMB 384
#define GROUPS 4
#define GC 96        // channels per group

typedef __attribute__((ext_vector_type(8))) short short8;   // 8 bf16 (4 VGPRs)
typedef __attribute__((ext_vector_type(4))) float f32x4;    // 4 fp32 acc / 16B vec

#define N_WPACK (GROUPS * 9 * 6 * 64 * 8)   // 110592 bf16 elements
#define PREP_BLOCKS ((N_WPACK + 255) / 256) // 432

__device__ __forceinline__ unsigned short f2bf(float f) {
    union { float f; unsigned u; } v; v.f = f;
    unsigned u = v.u + 0x7fffu + ((v.u >> 16) & 1u);  // RNE
    return (unsigned short)(u >> 16);
}

// ---------------------------------------------------------------------------
// Kernel 0 (fused): blocks [0,432) pack w1 -> bf16 MFMA B-frag layout;
// blocks [432,464) do per-batch cumsum + scatter frame->token idx.
// idx[b][t] = token j for cum[j-1] <= t < cum[j]; 0xFFFF past total.
// ---------------------------------------------------------------------------
__global__ __launch_bounds__(256) void prep_scan_kernel(const float* __restrict__ w1,
                                                        const int* __restrict__ dur,
                                                        unsigned short* __restrict__ wpack,
                                                        unsigned short* __restrict__ idx,
                                                        int t_out) {
    __shared__ int scum[TP];
    const int tid = threadIdx.x;

    if (blockIdx.x < PREP_BLOCKS) {
        int i = blockIdx.x * 256 + tid;
        if (i >= N_WPACK) return;
        int j = i & 7;
        int lane = (i >> 3) & 63;
        int rest = i >> 9;
        int nt = rest % 6; rest /= 6;
        int ks = rest % 9;
        int g = rest / 9;
        int oc = nt * 16 + (lane & 15);
        int kk = ks * 32 + (lane >> 4) * 8 + j;
        int k = kk / 96, ic = kk % 96;
        wpack[i] = f2bf(w1[((size_t)(g * GC + oc) * GC + ic) * 3 + k]);
        return;
    }

    const int b = blockIdx.x - PREP_BLOCKS;
    if (tid < 64) {
        const int* d = dur + b * TP;
        int offset = 0;
        for (int r = 0; r < 17; ++r) {
            int i2 = r * 64 + tid;
            int v = (i2 < TP) ? d[i2] : 0;
            int s = v;
#pragma unroll
            for (int off = 1; off < 64; off <<= 1) {
                int n = __shfl_up(s, off, 64);
                if (tid >= off) s += n;
            }
            if (i2 < TP) scum[i2] = s + offset;
            offset += __shfl(s, 63, 64);
        }
    }
    __syncthreads();

    unsigned short* ib = idx + (size_t)b * t_out;
    for (int j = tid; j < TP; j += 256) {
        int c = scum[j];
        int lo = j ? scum[j - 1] : 0;
        for (int f = lo; f < c; ++f) ib[f] = (unsigned short)j;
    }
    const int total = scum[TP - 1];
    for (int t = total + tid; t < t_out; t += 256) ib[t] = 0xFFFFu;
}

// ---------------------------------------------------------------------------
// Kernel 1: grouped conv (k=3,pad 1) + ReLU + 1x1 conv via bf16 MFMA.
// grid = (17 t-tiles of 64, 32 batches), block = 256 (4 waves = 4 groups).
// Wave g: 4x6 MFMA register tile (64 t-rows x 96 oc of group g):
//   per kstep: 4 ds_read_b128 A-frags + 6 coalesced 16B B-frags + 24 MFMAs.
// Epilogue: shuffle-reduce across lr, cross-group sum in LDS -> pred direct.
// ---------------------------------------------------------------------------
__global__ __launch_bounds__(256) void conv_mfma_kernel(const float* __restrict__ phoneme,
                                                        const float* __restrict__ silence,
                                                        const float* __restrict__ b1,
                                                        const float* __restrict__ w2,
                                                        const float* __restrict__ b2,
                                                        const unsigned short* __restrict__ wpack,
                                                        float* __restrict__ pred) {
    const int tile = blockIdx.x;
    const int b = blockIdx.y;
    const int t0 = tile * 64;

    __shared__ __align__(16) unsigned short xs[66][392];  // rows t0-1..t0+64, all 384 ch
    __shared__ float red[4][64];

    const int tid = threadIdx.x;

    // Stage 66 full rows (fp32 -> bf16), coalesced full-row float4 reads
    for (int e = tid; e < 66 * 96; e += 256) {
        int row = e / 96;
        int v = e - row * 96;
        int r = t0 - 1 + row;
        float4 val;
        if (r < 0 || r > T_IN) {
            val = make_float4(0.f, 0.f, 0.f, 0.f);
        } else if (r == T_IN) {
            val = *(const float4*)(silence + v * 4);
        } else {
            val = *(const float4*)(phoneme + ((size_t)(b * T_IN + r)) * EMB + v * 4);
        }
        ushort4 pk;
        pk.x = f2bf(val.x); pk.y = f2bf(val.y); pk.z = f2bf(val.z); pk.w = f2bf(val.w);
        *(ushort4*)&xs[row][v * 4] = pk;
    }
    __syncthreads();

    const int g = tid >> 6;     // wave = group
    const int lane = tid & 63;
    const int quad = lane >> 4;
    const int lr = lane & 15;

    f32x4 acc[4][6];
#pragma unroll
    for (int mt = 0; mt < 4; ++mt)
#pragma unroll
        for (int nt = 0; nt < 6; ++nt) acc[mt][nt] = (f32x4){0.f, 0.f, 0.f, 0.f};

    const unsigned short* wg = wpack + (size_t)g * 9 * 6 * 512;

#pragma unroll
    for (int ks = 0; ks < 9; ++ks) {
        const int tap = ks / 3;                               // kstep-uniform
        const int col = g * GC + 32 * (ks % 3) + quad * 8;    // channel offset
        short8 a[4];
#pragma unroll
        for (int mt = 0; mt < 4; ++mt)
            a[mt] = *(const short8*)&xs[mt * 16 + lr + tap][col];
#pragma unroll
        for (int nt = 0; nt < 6; ++nt) {
            short8 bf = *(const short8*)(wg + ((size_t)(ks * 6 + nt) * 64 + lane) * 8);
#pragma unroll
            for (int mt = 0; mt < 4; ++mt)
                acc[mt][nt] = __builtin_amdgcn_mfma_f32_16x16x32_bf16(a[mt], bf, acc[mt][nt], 0, 0, 0);
        }
    }

    // Epilogue: bias + ReLU + w2-dot partials; m = mt*16 + quad*4 + reg, oc col = lr
    float s[4][4];
#pragma unroll
    for (int mt = 0; mt < 4; ++mt)
#pragma unroll
        for (int reg = 0; reg < 4; ++reg) s[mt][reg] = 0.f;
#pragma unroll
    for (int nt = 0; nt < 6; ++nt) {
        int oc = g * GC + nt * 16 + lr;
        float bias = b1[oc];
        float wc = w2[oc];
#pragma unroll
        for (int mt = 0; mt < 4; ++mt)
#pragma unroll
            for (int reg = 0; reg < 4; ++reg) {
                float h = acc[mt][nt][reg] + bias;
                h = h > 0.f ? h : 0.f;
                s[mt][reg] += wc * h;
            }
    }
    // butterfly-sum across the 16 lr lanes (stays within each 16-lane group)
#pragma unroll
    for (int off = 1; off < 16; off <<= 1)
#pragma unroll
        for (int mt = 0; mt < 4; ++mt)
#pragma unroll
            for (int reg = 0; reg < 4; ++reg)
                s[mt][reg] += __shfl_xor(s[mt][reg], off, 64);
#pragma unroll
    for (int mt = 0; mt < 4; ++mt)
#pragma unroll
        for (int reg = 0; reg < 4; ++reg)
            if (lr == mt * 4 + reg) red[g][mt * 16 + quad * 4 + reg] = s[mt][reg];
    __syncthreads();

    if (tid < 64) {
        int t = t0 + tid;
        if (t < TP)
            pred[b * TP + t] = red[0][tid] + red[1][tid] + red[2][tid] + red[3][tid] + b2[0];
    }
}

// ---------------------------------------------------------------------------
// Kernel 2: streaming gather via precomputed idx. 32 B (2 float4) per thread,
// non-temporal stores (output never re-read -> keep L2/L3 for phoneme).
// nfe = t_out*96 is even, and e is even, so a pair never crosses a frame.
// grid = (ceil(t_out*96/512), 32).
// ---------------------------------------------------------------------------
__global__ __launch_bounds__(256) void gather_kernel(const float* __restrict__ phoneme,
                                                     const float* __restrict__ silence,
                                                     const unsigned short* __restrict__ idx,
                                                     float* __restrict__ out,
                                                     int t_out) {
    const int b = blockIdx.y;
    const int nfe = t_out * 96;                    // float4 count per batch
    int e = (blockIdx.x * 256 + threadIdx.x) * 2;  // even float4 index
    if (e >= nfe) return;
    int fl = e / 96;
    int v = e - fl * 96;
    unsigned short id = idx[(size_t)b * t_out + fl];
    f32x4 v0, v1;
    if (id == 0xFFFFu) {
        v0 = (f32x4){0.f, 0.f, 0.f, 0.f};
        v1 = v0;
    } else if (id == T_IN) {
        const f32x4* s4 = (const f32x4*)silence;
        v0 = s4[v]; v1 = s4[v + 1];
    } else {
        const f32x4* p = (const f32x4*)phoneme + ((size_t)b * T_IN + id) * 96 + v;
        v0 = p[0]; v1 = p[1];
    }
    f32x4* o = (f32x4*)out + (size_t)b * nfe + e;
    __builtin_nontemporal_store(v0, o);
    __builtin_nontemporal_store(v1, o + 1);
}

// ---------------------------------------------------------------------------
extern "C" void kernel_launch(void* const* d_in, const int* in_sizes, int n_in,
                              void* d_out, int out_size, void* d_ws, size_t ws_size,
                              hipStream_t stream) {
    const float* phoneme = (const float*)d_in[0];
    const float* silence = (const float*)d_in[1];
    const float* conv1_w = (const float*)d_in[2];
    const float* conv1_b = (const float*)d_in[3];
    const float* conv2_w = (const float*)d_in[4];
    const float* conv2_b = (const float*)d_in[5];
    const int* durations = (const int*)d_in[6];
    // d_in[7] = t_out on device; derive from out_size host-side instead.
    const int t_out = (out_size - BATCH * TP) / (BATCH * EMB);

    float* out_expanded = (float*)d_out;                            // [B, t_out, EMB]
    float* out_pred = (float*)d_out + (size_t)BATCH * t_out * EMB;  // [B, TP]

    // Workspace: idx [B][t_out] ushort, then wpack (16B-aligned)
    unsigned short* idx = (unsigned short*)d_ws;
    size_t idx_bytes = ((size_t)BATCH * t_out * sizeof(unsigned short) + 255) & ~(size_t)255;
    unsigned short* wpack = (unsigned short*)((char*)d_ws + idx_bytes);

    prep_scan_kernel<<<PREP_BLOCKS + BATCH, 256, 0, stream>>>(
        conv1_w, durations, wpack, idx, t_out);
    conv_mfma_kernel<<<dim3(17, BATCH), 256, 0, stream>>>(
        phoneme, silence, conv1_b, conv2_w, conv2_b, wpack, out_pred);
    gather_kernel<<<dim3((t_out * 96 / 2 + 255) / 256, BATCH), 256, 0, stream>>>(
        phoneme, silence, idx, out_expanded, t_out);
}